// Round 1
// baseline (4249.393 us; speedup 1.0000x reference)
//
#include <hip/hip_runtime.h>

#define Bsz 128
#define Tsz 1024
#define Dsz 128
#define Hsz 512
#define NBLK 256
#define NKC 20  // 640 / 32 K-chunks

typedef __attribute__((ext_vector_type(8))) short short8;
typedef __attribute__((ext_vector_type(4))) float f4;
typedef unsigned long long u64;
typedef unsigned int u32;

__device__ __forceinline__ short bf16_rne(float f) {
  unsigned u = __builtin_bit_cast(unsigned, f);
  u += 0x7fffu + ((u >> 16) & 1u);
  return (short)(u >> 16);
}
__device__ __forceinline__ float sigmoid_(float v) { return 1.f / (1.f + __expf(-v)); }

// Persistent LSTM, single-round-trip h exchange via self-validating tagged words.
//  - Each h element is stored as one u32: (bf16(h) << 16) | (t+1). Value and step
//    tag travel atomically in the same word, so readers poll DIRECTLY on the data:
//    tag >= t  <=>  this word is fresh. No flag array, no flag round trip, no
//    vmcnt-drain-before-flag, no third per-step barrier.
//  - Double buffer by step parity. Overwrite safety: a writer reaches its store at
//    step t+2 only after its poll at t+2 passed (all tags >= t+2), which implies
//    every block in the group finished its poll at t+1, i.e. already consumed the
//    step-t words being overwritten.
//  - Stale chunks are re-polled at 32-byte chunk granularity only; the load
//    latency (~600 cy) is the backoff — no s_sleep in the hot loop.
//  - x load + bf16 convert + LDS stage execute in the shadow of the in-flight
//    tagged h loads.
//  - Agent-scope relaxed atomics (bypass L1/L2 -> LLC) keep correctness
//    independent of block->XCD placement; bt = bx&7 grouping is perf-only.
__global__ __launch_bounds__(256, 1) void lstm_persist(
    const float* __restrict__ x, const float* __restrict__ W_ih,
    const float* __restrict__ W_hh, const float* __restrict__ b_ih,
    const float* __restrict__ b_hh, const float* __restrict__ W_fc,
    const float* __restrict__ b_fc, float* __restrict__ out,
    u32* hb0, u32* hb1)
{
  const int bx = blockIdx.x;
  const int bt = bx & 7, ks = bx >> 3;   // group = same bt (same XCD if round-robin)
  const int b0 = bt << 4, k0 = ks << 4;
  const int tx = threadIdx.x;
  const int wave = tx >> 6, lane = tx & 63;
  const int m = lane & 15, quad = lane >> 4;
  const int k_l = tx & 15, b_l = tx >> 4;   // update-phase ownership: (b_l, k_l)

  __shared__ short8 A_lds[NKC][64];      // 20 KB, pre-permuted A fragments
  __shared__ f4 gates_lds[4][64];        // 4 KB, per-gate D fragments
  __shared__ float fc_red[16][16];       // final FC reduction

  // ---- load W fragments into registers (once). Wave w = gate w. ----
  short8 wfrag[NKC];
  {
    const int j = wave * Hsz + k0 + m;   // W row = output column n of B-operand
    #pragma unroll
    for (int kc = 0; kc < NKC; ++kc) {
      const int kk = kc * 32 + quad * 8;
      const float* src = (kk < Dsz) ? (W_ih + (size_t)j * Dsz + kk)
                                    : (W_hh + (size_t)j * Hsz + (kk - Dsz));
      const f4* sv = (const f4*)src;
      f4 v0 = sv[0], v1 = sv[1];
      short8 w;
      w[0] = bf16_rne(v0[0]); w[1] = bf16_rne(v0[1]);
      w[2] = bf16_rne(v0[2]); w[3] = bf16_rne(v0[3]);
      w[4] = bf16_rne(v1[0]); w[5] = bf16_rne(v1[1]);
      w[6] = bf16_rne(v1[2]); w[7] = bf16_rne(v1[3]);
      wfrag[kc] = w;
    }
  }
  float bias[4];
  #pragma unroll
  for (int g = 0; g < 4; ++g)
    bias[g] = b_ih[g * Hsz + k0 + k_l] + b_hh[g * Hsz + k0 + k_l];
  float c_reg = 0.f;

  for (int t = 0; t < Tsz; ++t) {
    u32* hnext = (t & 1) ? hb1 : hb0;
    const u32* hprev = (t & 1) ? hb0 : hb1;

    // Issue x loads first: in flight (normal, L2-cached) while we poll h.
    const f4* xv = (const f4*)(x + (size_t)(b0 + m) * (Tsz * Dsz)
                               + (size_t)t * Dsz + wave * 32 + quad * 8);
    f4 v0 = xv[0], v1 = xv[1];

    if (t > 0) {
      // Issue ALL tagged h loads for this wave's 4 chunks (16 u64 in flight).
      u64 hv[16];
      #pragma unroll
      for (int q = 0; q < 4; ++q) {
        const int kc = 4 + wave * 4 + q;
        const u64* p = (const u64*)(hprev + (size_t)(b0 + m) * Hsz
                                    + (kc - 4) * 32 + quad * 8);
        #pragma unroll
        for (int j = 0; j < 4; ++j)
          hv[q * 4 + j] = __hip_atomic_load(p + j, __ATOMIC_RELAXED,
                                            __HIP_MEMORY_SCOPE_AGENT);
      }

      { // stage x chunk (kc = wave, K 0..127) while h loads are in flight
        short8 a;
        a[0] = bf16_rne(v0[0]); a[1] = bf16_rne(v0[1]);
        a[2] = bf16_rne(v0[2]); a[3] = bf16_rne(v0[3]);
        a[4] = bf16_rne(v1[0]); a[5] = bf16_rne(v1[1]);
        a[6] = bf16_rne(v1[2]); a[7] = bf16_rne(v1[3]);
        A_lds[wave][lane] = a;
      }

      // Poll: a chunk is consumable when all 8 of its tags >= t. Re-load only
      // stale chunks; unpack fresh ones straight to LDS.
      const unsigned tgt = (unsigned)t;
      unsigned todo = 0xFu;
      for (;;) {
        #pragma unroll
        for (int q = 0; q < 4; ++q) {
          if (todo & (1u << q)) {
            bool ok = true;
            #pragma unroll
            for (int j = 0; j < 4; ++j) {
              u64 v = hv[q * 4 + j];
              ok = ok && (((u32)v & 0xffffu) >= tgt)
                      && (((u32)(v >> 32) & 0xffffu) >= tgt);
            }
            if (ok) {
              short8 h8;
              #pragma unroll
              for (int j = 0; j < 4; ++j) {
                u64 v = hv[q * 4 + j];
                h8[2 * j]     = (short)((u32)v >> 16);
                h8[2 * j + 1] = (short)((u32)(v >> 32) >> 16);
              }
              A_lds[4 + wave * 4 + q][lane] = h8;
              todo &= ~(1u << q);
            }
          }
        }
        if (!__any(todo != 0)) break;
        #pragma unroll
        for (int q = 0; q < 4; ++q) {
          if (todo & (1u << q)) {
            const int kc = 4 + wave * 4 + q;
            const u64* p = (const u64*)(hprev + (size_t)(b0 + m) * Hsz
                                        + (kc - 4) * 32 + quad * 8);
            #pragma unroll
            for (int j = 0; j < 4; ++j)
              hv[q * 4 + j] = __hip_atomic_load(p + j, __ATOMIC_RELAXED,
                                                __HIP_MEMORY_SCOPE_AGENT);
          }
        }
      }
    } else {
      short8 z = {0, 0, 0, 0, 0, 0, 0, 0};
      #pragma unroll
      for (int q = 0; q < 4; ++q) A_lds[4 + wave * 4 + q][lane] = z;
      short8 a;
      a[0] = bf16_rne(v0[0]); a[1] = bf16_rne(v0[1]);
      a[2] = bf16_rne(v0[2]); a[3] = bf16_rne(v0[3]);
      a[4] = bf16_rne(v1[0]); a[5] = bf16_rne(v1[1]);
      a[6] = bf16_rne(v1[2]); a[7] = bf16_rne(v1[3]);
      A_lds[wave][lane] = a;
    }
    __syncthreads();   // barrier 1: A_lds complete before any wave's MFMA reads

    // ---- K loop: 20 x (ds_read_b128 + mfma), 2 accumulators for ILP
    f4 acc0 = {0.f, 0.f, 0.f, 0.f}, acc1 = {0.f, 0.f, 0.f, 0.f};
    #pragma unroll
    for (int kc = 0; kc < NKC; kc += 2) {
      acc0 = __builtin_amdgcn_mfma_f32_16x16x32_bf16(A_lds[kc][lane],     wfrag[kc],     acc0, 0, 0, 0);
      acc1 = __builtin_amdgcn_mfma_f32_16x16x32_bf16(A_lds[kc + 1][lane], wfrag[kc + 1], acc1, 0, 0, 0);
    }
    gates_lds[wave][lane] = acc0 + acc1;   // lane holds D[b=quad*4+r][n=lane&15]
    __syncthreads();   // barrier 2: gates_lds complete before combine reads

    { // ---- gate combine + state update: thread owns (b_l, k_l) ----
      const int lp = ((b_l >> 2) << 4) + k_l;  // lane holding row b_l
      const int r = b_l & 3;                   // reg index
      float pi = gates_lds[0][lp][r] + bias[0];
      float pf = gates_lds[1][lp][r] + bias[1];
      float pg = gates_lds[2][lp][r] + bias[2];
      float po = gates_lds[3][lp][r] + bias[3];
      float iv = sigmoid_(pi), fv = sigmoid_(pf), ov = sigmoid_(po);
      float gv = tanhf(pg);
      c_reg = fv * c_reg + iv * gv;
      float hvf = ov * tanhf(c_reg);
      // self-validating word: value in high 16, step tag in low 16
      u32 wrd = ((u32)(unsigned short)bf16_rne(hvf) << 16) | (u32)(t + 1);
      __hip_atomic_store(hnext + (size_t)(b0 + b_l) * Hsz + k0 + k_l, wrd,
                         __ATOMIC_RELAXED, __HIP_MEMORY_SCOPE_AGENT);
    }
    // no trailing barrier, no flag store: the tagged word IS the notification.
  }

  // ---- final FC: out[b] = sigmoid(h_last . W_fc + b_fc), ks==0 blocks ----
  if (ks == 0) {
    const u32* p = hb1 + (size_t)(b0 + b_l) * Hsz + k_l * 32;  // t=1023 wrote hb1
    u32 wv[32];
    for (;;) {
      #pragma unroll
      for (int j = 0; j < 32; ++j)
        wv[j] = __hip_atomic_load(p + j, __ATOMIC_RELAXED, __HIP_MEMORY_SCOPE_AGENT);
      bool ok = true;
      #pragma unroll
      for (int j = 0; j < 32; ++j)
        ok = ok && ((wv[j] & 0xffffu) >= (unsigned)Tsz);
      if (__all(ok)) break;
      __builtin_amdgcn_s_sleep(1);
    }
    float partial = 0.f;
    #pragma unroll
    for (int j = 0; j < 32; ++j)
      partial += __builtin_bit_cast(float, wv[j] & 0xffff0000u) * W_fc[k_l * 32 + j];
    fc_red[b_l][k_l] = partial;
    __syncthreads();
    if (k_l == 0) {
      float s = b_fc[0];
      #pragma unroll
      for (int e = 0; e < 16; ++e) s += fc_red[b_l][e];
      out[b0 + b_l] = sigmoid_(s);
    }
  }
}

extern "C" void kernel_launch(void* const* d_in, const int* in_sizes, int n_in,
                              void* d_out, int out_size, void* d_ws, size_t ws_size,
                              hipStream_t stream) {
  const float* x    = (const float*)d_in[0];
  const float* W_ih = (const float*)d_in[1];
  const float* W_hh = (const float*)d_in[2];
  const float* b_ih = (const float*)d_in[3];
  const float* b_hh = (const float*)d_in[4];
  const float* W_fc = (const float*)d_in[5];
  const float* b_fc = (const float*)d_in[6];
  float* out = (float*)d_out;
  char* ws = (char*)d_ws;
  // workspace: two tagged-u32 h buffers, 256 KB each (tags MUST be zeroed every
  // launch — stale tags from a previous run would satisfy the poll immediately)
  u32* hb0 = (u32*)ws;
  u32* hb1 = (u32*)(ws + (size_t)Bsz * Hsz * 4);
  hipMemsetAsync(ws, 0, (size_t)Bsz * Hsz * 8, stream);
  lstm_persist<<<NBLK, 256, 0, stream>>>(x, W_ih, W_hh, b_ih, b_hh, W_fc, b_fc,
                                         out, hb0, hb1);
}